// Round 3
// baseline (260.987 us; speedup 1.0000x reference)
//
#include <hip/hip_runtime.h>
#include <hip/hip_cooperative_groups.h>
#include <math.h>

namespace cg = cooperative_groups;

namespace {
constexpr int kTokens = 8192;
constexpr int kHS = 4096;
constexpr float kTol = 1e-4f;
constexpr float kEps = 1e-8f;
constexpr int kMaxIters = 1000;
constexpr int kSinkBlocks = 64;  // regular launch; 64 << 256 CUs -> co-resident
constexpr int kSplit = 4;        // K-split for k_logits occupancy
// ws layout: [tags: 2*64 uint][gdata: 2*64*64 f32]
//            [part: 512tile x 4split x 16 x 64 f32 (8MB)]
//            [whi: 512KB frag-packed bf16][wlo: 512KB]
constexpr size_t kTagFloats = 128;             // 2*64 uints
constexpr size_t kGdataFloats = 2 * 64 * 64;   // 8192
constexpr size_t kPartOff = kTagFloats + kGdataFloats;   // 8320 (16B aligned)
constexpr size_t kPartFloats = (size_t)kTokens * kSplit * 64;  // 2097152
constexpr size_t kWhiOff = kPartOff + kPartFloats;
constexpr size_t kWFragFloats = (size_t)(kHS / 32) * 4 * 64 * 4;  // 131072
constexpr size_t kWloOff = kWhiOff + kWFragFloats;
constexpr size_t kWsNeedFloats = kWloOff + kWFragFloats;
constexpr size_t kWtpFloats = (size_t)(kHS / 4) * 64 * 4;  // fallback only
}  // namespace

__device__ __forceinline__ float wave_sum(float v) {
#pragma unroll
  for (int o = 32; o; o >>= 1) v += __shfl_xor(v, o, 64);
  return v;
}

// ---------- bf16 split helpers ----------
typedef __attribute__((ext_vector_type(8))) short bf16x8;
typedef __attribute__((ext_vector_type(4))) float f32x4;

__device__ __forceinline__ unsigned short f2bf(float x) {
  unsigned u = __builtin_bit_cast(unsigned, x);
  u += 0x7fffu + ((u >> 16) & 1u);  // RNE; inputs are finite
  return (unsigned short)(u >> 16);
}

__device__ __forceinline__ void split8r(const float4 a, const float4 b,
                                        bf16x8& hi, bf16x8& lo) {
  const float v[8] = {a.x, a.y, a.z, a.w, b.x, b.y, b.z, b.w};
#pragma unroll
  for (int j = 0; j < 8; ++j) {
    const unsigned short h = f2bf(v[j]);
    const float hf = __builtin_bit_cast(float, (unsigned)h << 16);
    hi[j] = (short)h;
    lo[j] = (short)f2bf(v[j] - hf);  // exact two-term split, then RNE
  }
}

__device__ __forceinline__ void split8(const float* p, bf16x8& hi, bf16x8& lo) {
  split8r(*(const float4*)p, *(const float4*)(p + 4), hi, lo);
}

// ---------- K0: pre-convert W into fragment-packed bf16 hi/lo ----------
// Fragment (kk, n) lane l holds W[16n + (l&15)][kk*32 + (l>>4)*8 .. +8]
// (identical mapping to the verified round-1/2 B fragments).
__global__ void __launch_bounds__(256)
k_wsplit(const float* __restrict__ W, bf16x8* __restrict__ whi,
         bf16x8* __restrict__ wlo) {
  const int idx = blockIdx.x * 256 + threadIdx.x;
  const int lane = idx & 63;
  const int n = (idx >> 6) & 3;
  const int kk = idx >> 8;
  const int e = 16 * n + (lane & 15);
  const int k = kk * 32 + ((lane >> 4) << 3);
  bf16x8 hi, lo;
  split8(W + (size_t)e * kHS + k, hi, lo);
  whi[idx] = hi;
  wlo[idx] = lo;
}

// ---------- K1: bf16-split MFMA logits GEMM, 4-way K-split ----------
// Grid 2048 = 512 token-tiles x 4 K-splits; 256 thr (4 waves). Tile =
// 16 tokens x 64 experts; block covers K-quarter; wave w owns K=256.
// 5 blocks/CU (17KB LDS, ~90 VGPR) -> ~20 waves/CU for latency hiding.
// Deterministic per-split partials; k_sinkhorn head sums the 4.
__global__ void __launch_bounds__(256, 5)
k_logits(const float* __restrict__ X, const bf16x8* __restrict__ whi,
         const bf16x8* __restrict__ wlo, float* __restrict__ part) {
  const int tid = threadIdx.x;
  const int lane = tid & 63;
  const int wid = tid >> 6;            // 0..3
  const int tile = blockIdx.x >> 2;    // 0..511
  const int sig = blockIdx.x & 3;      // K-split 0..3
  const int t0 = tile * 16;
  const int r = lane & 15;             // A row / B col within fragment
  const int g = lane >> 4;             // k subgroup (8 consecutive k)
  const int kk0 = sig * 32 + wid * 8;  // global 32-wide k-step base

  const float* xp = X + (size_t)(t0 + r) * kHS + kk0 * 32 + g * 8;
  const bf16x8* bh_base = whi + (size_t)kk0 * 4 * 64 + lane;
  const bf16x8* bl_base = wlo + (size_t)kk0 * 4 * 64 + lane;

  f32x4 acc[4];
#pragma unroll
  for (int n = 0; n < 4; ++n) acc[n] = (f32x4){0.f, 0.f, 0.f, 0.f};

  // 2-deep X pipeline (static indices via full unroll)
  float4 xa[2][2];
  xa[0][0] = *(const float4*)(xp);
  xa[0][1] = *(const float4*)(xp + 4);
  xa[1][0] = *(const float4*)(xp + 32);
  xa[1][1] = *(const float4*)(xp + 36);

#pragma unroll
  for (int ks = 0; ks < 8; ++ks) {
    // issue W-frag loads for this ks (fly under the split VALU below)
    bf16x8 bh[4], bl[4];
#pragma unroll
    for (int n = 0; n < 4; ++n) {
      bh[n] = bh_base[(ks * 4 + n) * 64];
      bl[n] = bl_base[(ks * 4 + n) * 64];
    }
    const int cur = ks & 1;
    // issue X prefetch 2 ahead before consuming xa[cur]
    const float4 x0 = xa[cur][0];
    const float4 x1 = xa[cur][1];
    if (ks + 2 < 8) {
      xa[cur][0] = *(const float4*)(xp + (size_t)(ks + 2) * 32);
      xa[cur][1] = *(const float4*)(xp + (size_t)(ks + 2) * 32 + 4);
    }
    bf16x8 ah, al;
    split8r(x0, x1, ah, al);
#pragma unroll
    for (int n = 0; n < 4; ++n) {
      acc[n] = __builtin_amdgcn_mfma_f32_16x16x32_bf16(ah, bh[n], acc[n],
                                                       0, 0, 0);
      acc[n] = __builtin_amdgcn_mfma_f32_16x16x32_bf16(al, bh[n], acc[n],
                                                       0, 0, 0);
      acc[n] = __builtin_amdgcn_mfma_f32_16x16x32_bf16(ah, bl[n], acc[n],
                                                       0, 0, 0);
    }
  }

  // cross-wave K reduction: C/D layout col(expert)=16n+r, row(token)=g*4+q
  __shared__ __align__(16) float red[4][16][68];
#pragma unroll
  for (int n = 0; n < 4; ++n)
#pragma unroll
    for (int q = 0; q < 4; ++q)
      red[wid][g * 4 + q][n * 16 + r] = acc[n][q];
  __syncthreads();

  const int t = tid >> 4;          // 0..15
  const int e4 = (tid & 15) * 4;   // 0..60
  float4 s = *(const float4*)&red[0][t][e4];
#pragma unroll
  for (int w = 1; w < 4; ++w) {
    const float4 p = *(const float4*)&red[w][t][e4];
    s.x += p.x; s.y += p.y; s.z += p.z; s.w += p.w;
  }
  *(float4*)(part + ((size_t)(tile * 4 + sig) * 16 + t) * 64 + e4) = s;
}

// ---------- K2: sinkhorn + top-2 + softmax, custom tag barrier ----------
// Regular launch, 64 blocks x 1024 threads (co-resident: 64 << 256 CUs).
// Sync/iteration structure UNCHANGED from verified version; head now sums
// the 4 deterministic K-split partials.
__global__ void __launch_bounds__(1024, 1)
k_sinkhorn(const float* __restrict__ part, float* __restrict__ out,
           unsigned* __restrict__ tags, float* __restrict__ gdata) {
  const int tid = threadIdx.x;
  const int lane = tid & 63;
  const int wid = __builtin_amdgcn_readfirstlane(tid >> 6);  // 0..15
  const int blk = blockIdx.x;                                // 0..63
  __shared__ float lds[1024];

  const int t0 = blk * 128 + wid * 8;
  float lg[8], cst[8];
#pragma unroll
  for (int t = 0; t < 8; ++t) {
    const int row = t0 + t;
    const float* pb =
        part + ((size_t)(row >> 4) * kSplit * 16 + (row & 15)) * 64 + lane;
    const float a = pb[0] + pb[1024] + pb[2048] + pb[3072];
    lg[t] = a;
    cst[t] = expf(a);
  }

  // lane e holds d1[e]
  float d1 = 1.0f;
  float d0v[8];
  int buf = 0;
  for (int it = 0; it < kMaxIters; ++it) {
    float p = 0.0f;
#pragma unroll
    for (int t = 0; t < 8; ++t) {
      const float s = wave_sum(d1 * cst[t]);
      const float d0t = (1.0f / 8192.0f) / (s + kEps);
      d0v[t] = d0t;
      p = fmaf(d0t, cst[t], p);
    }
    __syncthreads();
    lds[wid * 64 + lane] = p;
    __syncthreads();
    const unsigned want = (unsigned)(it + 1);
    if (wid == 0) {
      float bp = 0.0f;
#pragma unroll
      for (int w = 0; w < 16; ++w) bp += lds[w * 64 + lane];
      // publish data then tag (release orders the wave's prior stores)
      __hip_atomic_store(&gdata[((size_t)buf * 64 + blk) * 64 + lane], bp,
                         __ATOMIC_RELAXED, __HIP_MEMORY_SCOPE_AGENT);
      __threadfence();
      if (lane == 0)
        __hip_atomic_store(&tags[buf * 64 + blk], want, __ATOMIC_RELEASE,
                           __HIP_MEMORY_SCOPE_AGENT);
      // poll: lane b waits for block b's tag
      while (__hip_atomic_load(&tags[buf * 64 + lane], __ATOMIC_ACQUIRE,
                               __HIP_MEMORY_SCOPE_AGENT) != want) {
        __builtin_amdgcn_s_sleep(1);
      }
    }
    __syncthreads();
    // every block reduces all 64 partials in identical order ->
    // bitwise-identical d1/err everywhere -> uniform loop exit
    float s2 = 0.0f;
#pragma unroll
    for (int i = 0; i < 4; ++i)
      s2 += __hip_atomic_load(
          &gdata[((size_t)buf * 64 + wid * 4 + i) * 64 + lane],
          __ATOMIC_RELAXED, __HIP_MEMORY_SCOPE_AGENT);
    lds[wid * 64 + lane] = s2;
    __syncthreads();
    float colsum = 0.0f;
#pragma unroll
    for (int w = 0; w < 16; ++w) colsum += lds[w * 64 + lane];
    const float d1n = (1.0f / 64.0f) / (colsum + kEps);
    const float err = wave_sum(fabsf(d1 - d1n)) * (1.0f / 64.0f);
    d1 = d1n;
    buf ^= 1;
    if (err <= kTol) break;
  }

  // top-2 of d1*cost*d0 + softmax scores
#pragma unroll
  for (int t = 0; t < 8; ++t) {
    const float lgv = lg[t];
    float m = lgv;
#pragma unroll
    for (int o = 32; o; o >>= 1) m = fmaxf(m, __shfl_xor(m, o, 64));
    const float ex = expf(lgv - m);
    const float den = wave_sum(ex);
    const float prob = ex / den;

    const float v = (d1 * cst[t]) * d0v[t];
    float v1 = v;
    int i1 = lane;
#pragma unroll
    for (int o = 32; o; o >>= 1) {
      const float ov = __shfl_xor(v1, o, 64);
      const int oi = __shfl_xor(i1, o, 64);
      if (ov > v1 || (ov == v1 && oi < i1)) { v1 = ov; i1 = oi; }
    }
    float v2 = (lane == i1) ? -INFINITY : v;
    int i2 = lane;
#pragma unroll
    for (int o = 32; o; o >>= 1) {
      const float ov = __shfl_xor(v2, o, 64);
      const int oi = __shfl_xor(i2, o, 64);
      if (ov > v2 || (ov == v2 && oi < i2)) { v2 = ov; i2 = oi; }
    }
    const float p1 = __shfl(prob, i1, 64);
    const float p2 = __shfl(prob, i2, 64);
    if (lane == 0) {
      const int row = t0 + t;
      out[row * 2 + 0] = p1;
      out[row * 2 + 1] = p2;
      out[2 * kTokens + row * 2 + 0] = (float)i1;
      out[2 * kTokens + row * 2 + 1] = (float)i2;
    }
  }
}

// ---------- fallback: round-1 monolithic cooperative kernel ----------
__global__ void __launch_bounds__(256, 1)
sinkhorn_router(const float* __restrict__ X, const float* __restrict__ W,
                float* __restrict__ out, float* __restrict__ ws) {
  cg::grid_group grid = cg::this_grid();
  const int tid = threadIdx.x;
  const int lane = tid & 63;
  const int wid = __builtin_amdgcn_readfirstlane(tid >> 6);
  const int blk = blockIdx.x;

  float4* wtp = reinterpret_cast<float4*>(ws);
  float* gpart = ws + kWtpFloats;
  __shared__ float lds[256];

  {
    const int j = blk * 256 + tid;
    const int e = j & 63;
    const int k4 = j >> 6;
    wtp[j] = *reinterpret_cast<const float4*>(W + (size_t)e * kHS + 4 * (size_t)k4);
  }
  grid.sync();

  const int t0 = blk * 32 + wid * 8;
  const float* xb = X + (size_t)t0 * kHS;
  float lg[8];
#pragma unroll
  for (int t = 0; t < 8; ++t) lg[t] = 0.0f;

#pragma unroll 2
  for (int k4 = 0; k4 < kHS / 4; ++k4) {
    const float4 w = wtp[k4 * 64 + lane];
#pragma unroll
    for (int t = 0; t < 8; ++t) {
      const float* xr = xb + (size_t)t * kHS + 4 * (size_t)k4;
      float a = lg[t];
      a = fmaf(xr[0], w.x, a);
      a = fmaf(xr[1], w.y, a);
      a = fmaf(xr[2], w.z, a);
      a = fmaf(xr[3], w.w, a);
      lg[t] = a;
    }
  }

  float cst[8];
#pragma unroll
  for (int t = 0; t < 8; ++t) cst[t] = expf(lg[t]);

  float d1 = 1.0f;
  float d0v[8];
  int buf = 0;
  for (int it = 0; it < kMaxIters; ++it) {
    float p = 0.0f;
#pragma unroll
    for (int t = 0; t < 8; ++t) {
      const float s = wave_sum(d1 * cst[t]);
      const float d0t = (1.0f / 8192.0f) / (s + kEps);
      d0v[t] = d0t;
      p = fmaf(d0t, cst[t], p);
    }
    __syncthreads();
    lds[wid * 64 + lane] = p;
    __syncthreads();
    if (wid == 0) {
      const float bp =
          lds[lane] + lds[64 + lane] + lds[128 + lane] + lds[192 + lane];
      gpart[buf * (256 * 64) + blk * 64 + lane] = bp;
    }
    grid.sync();
    const float* gp = gpart + buf * (256 * 64);
    float s = 0.0f;
#pragma unroll 8
    for (int b = 0; b < 64; ++b) s += gp[(wid * 64 + b) * 64 + lane];
    lds[wid * 64 + lane] = s;
    __syncthreads();
    const float colsum =
        lds[lane] + lds[64 + lane] + lds[128 + lane] + lds[192 + lane];
    const float d1n = (1.0f / 64.0f) / (colsum + kEps);
    const float err = wave_sum(fabsf(d1 - d1n)) * (1.0f / 64.0f);
    d1 = d1n;
    buf ^= 1;
    if (err <= kTol) break;
  }

#pragma unroll
  for (int t = 0; t < 8; ++t) {
    const float lgv = lg[t];
    float m = lgv;
#pragma unroll
    for (int o = 32; o; o >>= 1) m = fmaxf(m, __shfl_xor(m, o, 64));
    const float ex = expf(lgv - m);
    const float den = wave_sum(ex);
    const float prob = ex / den;

    const float v = (d1 * cst[t]) * d0v[t];
    float v1 = v;
    int i1 = lane;
#pragma unroll
    for (int o = 32; o; o >>= 1) {
      const float ov = __shfl_xor(v1, o, 64);
      const int oi = __shfl_xor(i1, o, 64);
      if (ov > v1 || (ov == v1 && oi < i1)) { v1 = ov; i1 = oi; }
    }
    float v2 = (lane == i1) ? -INFINITY : v;
    int i2 = lane;
#pragma unroll
    for (int o = 32; o; o >>= 1) {
      const float ov = __shfl_xor(v2, o, 64);
      const int oi = __shfl_xor(i2, o, 64);
      if (ov > v2 || (ov == v2 && oi < i2)) { v2 = ov; i2 = oi; }
    }
    const float p1 = __shfl(prob, i1, 64);
    const float p2 = __shfl(prob, i2, 64);
    if (lane == 0) {
      const int row = t0 + t;
      out[row * 2 + 0] = p1;
      out[row * 2 + 1] = p2;
      out[2 * kTokens + row * 2 + 0] = (float)i1;
      out[2 * kTokens + row * 2 + 1] = (float)i2;
    }
  }
}

extern "C" void kernel_launch(void* const* d_in, const int* in_sizes, int n_in,
                              void* d_out, int out_size, void* d_ws,
                              size_t ws_size, hipStream_t stream) {
  const float* X = (const float*)d_in[0];
  const float* W = (const float*)d_in[1];
  float* out = (float*)d_out;
  float* ws = (float*)d_ws;

  const size_t need = kWsNeedFloats * sizeof(float);
  if (ws_size < need) {
    void* args[] = {(void*)&X, (void*)&W, (void*)&out, (void*)&ws};
    hipLaunchCooperativeKernel((const void*)sinkhorn_router, dim3(256),
                               dim3(256), args, 0, stream);
    return;
  }

  unsigned* tags = reinterpret_cast<unsigned*>(ws);
  float* gdata = ws + kTagFloats;
  float* part = ws + kPartOff;
  bf16x8* whi = reinterpret_cast<bf16x8*>(ws + kWhiOff);
  bf16x8* wlo = reinterpret_cast<bf16x8*>(ws + kWloOff);

  hipLaunchKernelGGL(k_wsplit, dim3((kHS / 32) * 4 * 64 / 256), dim3(256), 0,
                     stream, W, whi, wlo);
  hipLaunchKernelGGL(k_logits, dim3((kTokens / 16) * kSplit), dim3(256), 0,
                     stream, X, whi, wlo, part);
  hipLaunchKernelGGL(k_sinkhorn, dim3(kSinkBlocks), dim3(1024), 0, stream,
                     part, out, tags, gdata);
}

// Round 4
// 254.903 us; speedup vs baseline: 1.0239x; 1.0239x over previous
//
#include <hip/hip_runtime.h>
#include <hip/hip_cooperative_groups.h>
#include <math.h>

namespace cg = cooperative_groups;

namespace {
constexpr int kTokens = 8192;
constexpr int kHS = 4096;
constexpr float kTol = 1e-4f;
constexpr float kEps = 1e-8f;
constexpr int kMaxIters = 1000;
constexpr int kSinkBlocks = 32;  // regular launch; 32 << 256 CUs -> co-resident
constexpr int kSplit = 2;        // K-split for k_logits
// ws layout: [gdata64: 2*64*64 u64 = 64KB][part: 512 x 32 x 64 f32 (4MB)]
//            [whi: 512KB frag-packed bf16][wlo: 512KB]
constexpr size_t kGdataFloats = 2 * 64 * 64 * 2;          // 16384 f32-equiv
constexpr size_t kPartOff = kGdataFloats;                 // 16384
constexpr size_t kPartFloats = (size_t)kTokens * kSplit * 64;  // 1048576
constexpr size_t kWhiOff = kPartOff + kPartFloats;        // 1064960
constexpr size_t kWFragFloats = (size_t)(kHS / 32) * 4 * 64 * 4;  // 131072
constexpr size_t kWloOff = kWhiOff + kWFragFloats;
constexpr size_t kWsNeedFloats = kWloOff + kWFragFloats;
constexpr size_t kWtpFloats = (size_t)(kHS / 4) * 64 * 4;  // fallback only
}  // namespace

__device__ __forceinline__ float wave_sum(float v) {
#pragma unroll
  for (int o = 32; o; o >>= 1) v += __shfl_xor(v, o, 64);
  return v;
}

// ---------- bf16 split helpers ----------
typedef __attribute__((ext_vector_type(8))) short bf16x8;
typedef __attribute__((ext_vector_type(4))) float f32x4;

__device__ __forceinline__ unsigned short f2bf(float x) {
  unsigned u = __builtin_bit_cast(unsigned, x);
  u += 0x7fffu + ((u >> 16) & 1u);  // RNE; inputs are finite
  return (unsigned short)(u >> 16);
}

__device__ __forceinline__ void split8r(const float4 a, const float4 b,
                                        bf16x8& hi, bf16x8& lo) {
  const float v[8] = {a.x, a.y, a.z, a.w, b.x, b.y, b.z, b.w};
#pragma unroll
  for (int j = 0; j < 8; ++j) {
    const unsigned short h = f2bf(v[j]);
    const float hf = __builtin_bit_cast(float, (unsigned)h << 16);
    hi[j] = (short)h;
    lo[j] = (short)f2bf(v[j] - hf);  // exact two-term split, then RNE
  }
}

__device__ __forceinline__ void split8(const float* p, bf16x8& hi, bf16x8& lo) {
  split8r(*(const float4*)p, *(const float4*)(p + 4), hi, lo);
}

// ---------- K0: pre-convert W into fragment-packed bf16 hi/lo ----------
// Fragment (kk, n) lane l holds W[16n + (l&15)][kk*32 + (l>>4)*8 .. +8]
// (identical mapping to the verified round-1/2/3 B fragments).
__global__ void __launch_bounds__(256)
k_wsplit(const float* __restrict__ W, bf16x8* __restrict__ whi,
         bf16x8* __restrict__ wlo) {
  const int idx = blockIdx.x * 256 + threadIdx.x;
  const int lane = idx & 63;
  const int n = (idx >> 6) & 3;
  const int kk = idx >> 8;
  const int e = 16 * n + (lane & 15);
  const int k = kk * 32 + ((lane >> 4) << 3);
  bf16x8 hi, lo;
  split8(W + (size_t)e * kHS + k, hi, lo);
  whi[idx] = hi;
  wlo[idx] = lo;
}

// ---------- K1 v4: bf16-split MFMA GEMM, 2x compute density + dbuf ----------
// Grid 512 = 256 token-tiles x 2 K-splits; 256 thr (4 waves). Tile =
// 32 tokens x 64 experts; wave owns K=512 (16 ks-steps of 32).
// Per ks: 24 MFMA per 8 B-frag loads (vs 12 in r3); B and X for ks+1 are
// loaded into NAMED alternate buffers BEFORE the MFMA cluster of ks, so
// L2/HBM latency hides under ~320cy of MFMA+split VALU. ~160 VGPR.
__device__ __forceinline__ void ldB(const bf16x8* __restrict__ bhp,
                                    const bf16x8* __restrict__ blp, int ks,
                                    bf16x8 (&bh)[4], bf16x8 (&bl)[4]) {
#pragma unroll
  for (int n = 0; n < 4; ++n) {
    bh[n] = bhp[(ks * 4 + n) * 64];
    bl[n] = blp[(ks * 4 + n) * 64];
  }
}

__device__ __forceinline__ void ldX(const float* __restrict__ xp, int ks,
                                    float4 (&x)[2][2]) {
#pragma unroll
  for (int m = 0; m < 2; ++m) {
    x[m][0] = *(const float4*)(xp + (size_t)(16 * m) * kHS + ks * 32);
    x[m][1] = *(const float4*)(xp + (size_t)(16 * m) * kHS + ks * 32 + 4);
  }
}

__device__ __forceinline__ void mstep(const float4 (&x)[2][2],
                                      const bf16x8 (&bh)[4],
                                      const bf16x8 (&bl)[4],
                                      f32x4 (&acc)[2][4]) {
#pragma unroll
  for (int m = 0; m < 2; ++m) {
    bf16x8 ah, al;
    split8r(x[m][0], x[m][1], ah, al);
#pragma unroll
    for (int n = 0; n < 4; ++n) {
      acc[m][n] =
          __builtin_amdgcn_mfma_f32_16x16x32_bf16(ah, bh[n], acc[m][n], 0, 0, 0);
      acc[m][n] =
          __builtin_amdgcn_mfma_f32_16x16x32_bf16(al, bh[n], acc[m][n], 0, 0, 0);
      acc[m][n] =
          __builtin_amdgcn_mfma_f32_16x16x32_bf16(ah, bl[n], acc[m][n], 0, 0, 0);
    }
  }
}

__global__ void __launch_bounds__(256, 2)
k_logits(const float* __restrict__ X, const bf16x8* __restrict__ whi,
         const bf16x8* __restrict__ wlo, float* __restrict__ part) {
  const int tid = threadIdx.x;
  const int lane = tid & 63;
  const int wid = tid >> 6;            // 0..3
  const int tile = blockIdx.x >> 1;    // 0..255
  const int sig = blockIdx.x & 1;      // K-split 0..1
  const int t0 = tile * 32;
  const int r = lane & 15;             // A row / B col within fragment
  const int g = lane >> 4;             // k subgroup (8 consecutive k)
  const int kk0 = sig * 64 + wid * 16; // 32-wide ks-step base; wave K=512

  const float* xp = X + (size_t)(t0 + r) * kHS + kk0 * 32 + g * 8;
  const bf16x8* bhp = whi + (size_t)kk0 * 4 * 64 + lane;
  const bf16x8* blp = wlo + (size_t)kk0 * 4 * 64 + lane;

  f32x4 acc[2][4];
#pragma unroll
  for (int m = 0; m < 2; ++m)
#pragma unroll
    for (int n = 0; n < 4; ++n) acc[m][n] = (f32x4){0.f, 0.f, 0.f, 0.f};

  bf16x8 bhA[4], blA[4], bhB[4], blB[4];
  float4 xA[2][2], xB[2][2];
  ldB(bhp, blp, 0, bhA, blA);
  ldX(xp, 0, xA);

#pragma unroll
  for (int kp = 0; kp < 8; ++kp) {
    const int ks = 2 * kp;
    // prefetch ks+1 into B-set BEFORE consuming A-set
    if (ks + 1 < 16) {
      ldB(bhp, blp, ks + 1, bhB, blB);
      ldX(xp, ks + 1, xB);
    }
    mstep(xA, bhA, blA, acc);
    // prefetch ks+2 into A-set BEFORE consuming B-set
    if (ks + 2 < 16) {
      ldB(bhp, blp, ks + 2, bhA, blA);
      ldX(xp, ks + 2, xA);
    }
    mstep(xB, bhB, blB, acc);
  }

  // cross-wave K reduction: C/D layout col(expert)=16n+r, row(token)=g*4+q
  __shared__ __align__(16) float red[4][32][68];
#pragma unroll
  for (int m = 0; m < 2; ++m)
#pragma unroll
    for (int n = 0; n < 4; ++n)
#pragma unroll
      for (int q = 0; q < 4; ++q)
        red[wid][m * 16 + g * 4 + q][n * 16 + r] = acc[m][n][q];
  __syncthreads();

#pragma unroll
  for (int rep = 0; rep < 2; ++rep) {
    const int idx = rep * 256 + tid;
    const int t = idx >> 4;          // 0..31
    const int e4 = (idx & 15) * 4;   // 0..60
    float4 s = *(const float4*)&red[0][t][e4];
#pragma unroll
    for (int w = 1; w < 4; ++w) {
      const float4 p = *(const float4*)&red[w][t][e4];
      s.x += p.x; s.y += p.y; s.z += p.z; s.w += p.w;
    }
    *(float4*)(part + ((size_t)(tile * 2 + sig) * 32 + t) * 64 + e4) = s;
  }
}

// ---------- K2: sinkhorn + top-2 + softmax, packed data+tag barrier ----------
// 32 blocks x 1024 threads (co-resident). Each block publishes its 64
// column partials as (gen<<32 | float_bits) uint64 (double-buffered by
// it&1; a block is at most 1 generation ahead of any reader of its slot,
// and slots are reused 2 generations apart -> no overwrite race). Readers
// poll the packed word directly: tag+data arrive atomically, no fence, no
// second visibility hop. gdata64 is zeroed in-stream before launch.
__global__ void __launch_bounds__(1024, 1)
k_sinkhorn(const float* __restrict__ part, float* __restrict__ out,
           unsigned long long* __restrict__ gdata) {
  const int tid = threadIdx.x;
  const int lane = tid & 63;
  const int wid = __builtin_amdgcn_readfirstlane(tid >> 6);  // 0..15
  const int blk = blockIdx.x;                                // 0..31
  __shared__ float lds[1024];

  const int t0 = blk * 256 + wid * 16;
  float lg[16], cst[16];
#pragma unroll
  for (int t = 0; t < 16; ++t) {
    const int row = t0 + t;
    const float* pb =
        part + ((size_t)(row >> 5) * 2 * 32 + (row & 31)) * 64 + lane;
    const float a = pb[0] + pb[2048];  // sum the 2 deterministic K-splits
    lg[t] = a;
    cst[t] = expf(a);
  }

  // lane e holds d1[e]
  float d1 = 1.0f;
  float d0v[16];
  for (int it = 0; it < kMaxIters; ++it) {
    float p = 0.0f;
#pragma unroll
    for (int t = 0; t < 16; ++t) {
      const float s = wave_sum(d1 * cst[t]);
      const float d0t = (1.0f / 8192.0f) / (s + kEps);
      d0v[t] = d0t;
      p = fmaf(d0t, cst[t], p);
    }
    __syncthreads();
    lds[wid * 64 + lane] = p;
    __syncthreads();
    const unsigned want = (unsigned)(it + 1);
    const int buf = it & 1;
    if (wid == 0) {
      float bp = 0.0f;
#pragma unroll
      for (int w = 0; w < 16; ++w) bp += lds[w * 64 + lane];
      const unsigned long long pk =
          ((unsigned long long)want << 32) |
          (unsigned long long)__builtin_bit_cast(unsigned, bp);
      __hip_atomic_store(&gdata[((size_t)buf * 64 + blk) * 64 + lane], pk,
                         __ATOMIC_RELAXED, __HIP_MEMORY_SCOPE_AGENT);
    }
    __syncthreads();  // bp's lds reads complete before lds reuse below
    // every thread polls its 2 packed entries; all blocks then reduce the
    // identical 32 values in identical order -> bitwise-identical d1/err
    float s2 = 0.0f;
#pragma unroll
    for (int i = 0; i < 2; ++i) {
      const size_t gi = ((size_t)buf * 64 + wid * 2 + i) * 64 + lane;
      unsigned long long v;
      while (((v = __hip_atomic_load(&gdata[gi], __ATOMIC_RELAXED,
                                     __HIP_MEMORY_SCOPE_AGENT)) >>
              32) != want) {
        __builtin_amdgcn_s_sleep(1);
      }
      s2 += __builtin_bit_cast(float, (unsigned)(v & 0xffffffffu));
    }
    lds[wid * 64 + lane] = s2;
    __syncthreads();
    float colsum = 0.0f;
#pragma unroll
    for (int w = 0; w < 16; ++w) colsum += lds[w * 64 + lane];
    const float d1n = (1.0f / 64.0f) / (colsum + kEps);
    const float err = wave_sum(fabsf(d1 - d1n)) * (1.0f / 64.0f);
    d1 = d1n;
    if (err <= kTol) break;
  }

  // top-2 of d1*cost*d0 + softmax scores
#pragma unroll
  for (int t = 0; t < 16; ++t) {
    const float lgv = lg[t];
    float m = lgv;
#pragma unroll
    for (int o = 32; o; o >>= 1) m = fmaxf(m, __shfl_xor(m, o, 64));
    const float ex = expf(lgv - m);
    const float den = wave_sum(ex);
    const float prob = ex / den;

    const float v = (d1 * cst[t]) * d0v[t];
    float v1 = v;
    int i1 = lane;
#pragma unroll
    for (int o = 32; o; o >>= 1) {
      const float ov = __shfl_xor(v1, o, 64);
      const int oi = __shfl_xor(i1, o, 64);
      if (ov > v1 || (ov == v1 && oi < i1)) { v1 = ov; i1 = oi; }
    }
    float v2 = (lane == i1) ? -INFINITY : v;
    int i2 = lane;
#pragma unroll
    for (int o = 32; o; o >>= 1) {
      const float ov = __shfl_xor(v2, o, 64);
      const int oi = __shfl_xor(i2, o, 64);
      if (ov > v2 || (ov == v2 && oi < i2)) { v2 = ov; i2 = oi; }
    }
    const float p1 = __shfl(prob, i1, 64);
    const float p2 = __shfl(prob, i2, 64);
    if (lane == 0) {
      const int row = t0 + t;
      out[row * 2 + 0] = p1;
      out[row * 2 + 1] = p2;
      out[2 * kTokens + row * 2 + 0] = (float)i1;
      out[2 * kTokens + row * 2 + 1] = (float)i2;
    }
  }
}

// ---------- fallback: round-1 monolithic cooperative kernel ----------
__global__ void __launch_bounds__(256, 1)
sinkhorn_router(const float* __restrict__ X, const float* __restrict__ W,
                float* __restrict__ out, float* __restrict__ ws) {
  cg::grid_group grid = cg::this_grid();
  const int tid = threadIdx.x;
  const int lane = tid & 63;
  const int wid = __builtin_amdgcn_readfirstlane(tid >> 6);
  const int blk = blockIdx.x;

  float4* wtp = reinterpret_cast<float4*>(ws);
  float* gpart = ws + kWtpFloats;
  __shared__ float lds[256];

  {
    const int j = blk * 256 + tid;
    const int e = j & 63;
    const int k4 = j >> 6;
    wtp[j] = *reinterpret_cast<const float4*>(W + (size_t)e * kHS + 4 * (size_t)k4);
  }
  grid.sync();

  const int t0 = blk * 32 + wid * 8;
  const float* xb = X + (size_t)t0 * kHS;
  float lg[8];
#pragma unroll
  for (int t = 0; t < 8; ++t) lg[t] = 0.0f;

#pragma unroll 2
  for (int k4 = 0; k4 < kHS / 4; ++k4) {
    const float4 w = wtp[k4 * 64 + lane];
#pragma unroll
    for (int t = 0; t < 8; ++t) {
      const float* xr = xb + (size_t)t * kHS + 4 * (size_t)k4;
      float a = lg[t];
      a = fmaf(xr[0], w.x, a);
      a = fmaf(xr[1], w.y, a);
      a = fmaf(xr[2], w.z, a);
      a = fmaf(xr[3], w.w, a);
      lg[t] = a;
    }
  }

  float cst[8];
#pragma unroll
  for (int t = 0; t < 8; ++t) cst[t] = expf(lg[t]);

  float d1 = 1.0f;
  float d0v[8];
  int buf = 0;
  for (int it = 0; it < kMaxIters; ++it) {
    float p = 0.0f;
#pragma unroll
    for (int t = 0; t < 8; ++t) {
      const float s = wave_sum(d1 * cst[t]);
      const float d0t = (1.0f / 8192.0f) / (s + kEps);
      d0v[t] = d0t;
      p = fmaf(d0t, cst[t], p);
    }
    __syncthreads();
    lds[wid * 64 + lane] = p;
    __syncthreads();
    if (wid == 0) {
      const float bp =
          lds[lane] + lds[64 + lane] + lds[128 + lane] + lds[192 + lane];
      gpart[buf * (256 * 64) + blk * 64 + lane] = bp;
    }
    grid.sync();
    const float* gp = gpart + buf * (256 * 64);
    float s = 0.0f;
#pragma unroll 8
    for (int b = 0; b < 64; ++b) s += gp[(wid * 64 + b) * 64 + lane];
    lds[wid * 64 + lane] = s;
    __syncthreads();
    const float colsum =
        lds[lane] + lds[64 + lane] + lds[128 + lane] + lds[192 + lane];
    const float d1n = (1.0f / 64.0f) / (colsum + kEps);
    const float err = wave_sum(fabsf(d1 - d1n)) * (1.0f / 64.0f);
    d1 = d1n;
    buf ^= 1;
    if (err <= kTol) break;
  }

#pragma unroll
  for (int t = 0; t < 8; ++t) {
    const float lgv = lg[t];
    float m = lgv;
#pragma unroll
    for (int o = 32; o; o >>= 1) m = fmaxf(m, __shfl_xor(m, o, 64));
    const float ex = expf(lgv - m);
    const float den = wave_sum(ex);
    const float prob = ex / den;

    const float v = (d1 * cst[t]) * d0v[t];
    float v1 = v;
    int i1 = lane;
#pragma unroll
    for (int o = 32; o; o >>= 1) {
      const float ov = __shfl_xor(v1, o, 64);
      const int oi = __shfl_xor(i1, o, 64);
      if (ov > v1 || (ov == v1 && oi < i1)) { v1 = ov; i1 = oi; }
    }
    float v2 = (lane == i1) ? -INFINITY : v;
    int i2 = lane;
#pragma unroll
    for (int o = 32; o; o >>= 1) {
      const float ov = __shfl_xor(v2, o, 64);
      const int oi = __shfl_xor(i2, o, 64);
      if (ov > v2 || (ov == v2 && oi < i2)) { v2 = ov; i2 = oi; }
    }
    const float p1 = __shfl(prob, i1, 64);
    const float p2 = __shfl(prob, i2, 64);
    if (lane == 0) {
      const int row = t0 + t;
      out[row * 2 + 0] = p1;
      out[row * 2 + 1] = p2;
      out[2 * kTokens + row * 2 + 0] = (float)i1;
      out[2 * kTokens + row * 2 + 1] = (float)i2;
    }
  }
}

extern "C" void kernel_launch(void* const* d_in, const int* in_sizes, int n_in,
                              void* d_out, int out_size, void* d_ws,
                              size_t ws_size, hipStream_t stream) {
  const float* X = (const float*)d_in[0];
  const float* W = (const float*)d_in[1];
  float* out = (float*)d_out;
  float* ws = (float*)d_ws;

  const size_t need = kWsNeedFloats * sizeof(float);
  if (ws_size < need) {
    void* args[] = {(void*)&X, (void*)&W, (void*)&out, (void*)&ws};
    hipLaunchCooperativeKernel((const void*)sinkhorn_router, dim3(256),
                               dim3(256), args, 0, stream);
    return;
  }

  unsigned long long* gdata = reinterpret_cast<unsigned long long*>(ws);
  float* part = ws + kPartOff;
  bf16x8* whi = reinterpret_cast<bf16x8*>(ws + kWhiOff);
  bf16x8* wlo = reinterpret_cast<bf16x8*>(ws + kWloOff);

  // zero the packed-tag exchange area (ws is poisoned by the harness)
  hipMemsetAsync(gdata, 0, kGdataFloats * sizeof(float), stream);
  hipLaunchKernelGGL(k_wsplit, dim3((kHS / 32) * 4 * 64 / 256), dim3(256), 0,
                     stream, W, whi, wlo);
  hipLaunchKernelGGL(k_logits, dim3((kTokens / 32) * kSplit), dim3(256), 0,
                     stream, X, whi, wlo, part);
  hipLaunchKernelGGL(k_sinkhorn, dim3(kSinkBlocks), dim3(1024), 0, stream,
                     part, out, gdata);
}